// Round 16
// baseline (106.219 us; speedup 1.0000x reference)
//
#include <hip/hip_runtime.h>
#include <hip/hip_bf16.h>
#include <hip/hip_fp16.h>

// SJLT projection: out[b, idx[d,c]] += x[b,d] * (2*sign[d,c]-1)
// B=64, D=262144, C=4, P=4096
//
// R16. R13/14/15 bracket the LDS-hist design at 41-50us (hist RMW chain +
// ~25 VALU/entry). Redesign of k_process: REGISTER accumulators.
//   - lane = b (full 64-wide row per entry): update is per-lane ->
//     race-free, order-free, NO dup-merge, NO hist LDS, NO collisions.
//   - acc = 16 NAMED __half vars (rule-20-proof); runtime po routed by a
//     uniform scalar branch tree (po via readfirstlane -> SGPR ->
//     s_cmp/s_cbranch on the scalar pipe, overlaps VALU).
//   - per entry: 1 ushort gather (uniform row base + lane*2, saddr form),
//     1 XOR (f16 sign), 1 v_add_f16 = ~3 VALU (vs ~25).
//   - gathers hoisted 4/batch before the branchy adds (4 in flight).
//   - queues padded to x4 with bit14-dummy entries -> no tail paths.
//   - halfbin blocks (8 waves x 16-wide), G_DS=2, grid 1024 = 4/CU,
//     LDS ~7.5KB, launch_bounds(512,8) -> target 32 waves/CU.
// binpack/transpose/reduce: R15 verbatim (NDG=32).

constexpr int B_DIM = 64;
constexpr int D_DIM = 262144;
constexpr int P_DIM = 4096;

constexpr int NDS   = 64;
constexpr int SLICE = D_DIM / NDS;      // 4096
constexpr int NBIN  = 16;               // binpack bins (256-wide)
constexpr int NSC   = 16;               // scanners per dslice
constexpr int SC_D  = SLICE / NSC;      // 256
constexpr int BCAP  = 128;              // per (dslice,sc,bin): mean 64, 8 sigma
constexpr int NHB   = 32;               // half-bins (128-wide)
constexpr int G_DS  = 2;                // dslices per process block
constexpr int NDG   = NDS / G_DS;       // 32
constexpr int WPB   = 8;
constexpr int PR_W  = 16;
constexpr int NPR   = P_DIM / PR_W;     // 256
constexpr int QCAP  = 28;               // mean 4 (Poisson), clamp 24, pad to x4

// ---- ws layout ----
constexpr size_t REG_OFF   = 0;
constexpr size_t REG_BYTES = (size_t)NDS * NSC * NBIN * BCAP * 4;          // 8.4 MB
constexpr size_t CNT_OFF   = REG_OFF + REG_BYTES;
constexpr size_t CNT_BYTES = (size_t)NDS * NSC * NBIN * 4;                 // 64 KB
constexpr size_t XT_OFF    = CNT_OFF + CNT_BYTES;
constexpr size_t XT_BYTES  = (size_t)D_DIM * B_DIM * 2;                    // 33.5 MB
constexpr size_t PART_OFF  = XT_OFF + XT_BYTES;
constexpr size_t PART_BYTES = (size_t)NPR * NDG * PR_W * B_DIM * 2;        // 16.8 MB
constexpr size_t WS_NEED   = PART_OFF + PART_BYTES;                        // ~59 MB

// ---------------- K1: one-pass pack + bin (proven) ----------------
// entry u32: bits 0-18 rowbyte (dloc-in-slice*128), 19-26 p&255,
//            bit 31 = (sv^1) -> negate when set.
__global__ __launch_bounds__(256) void k_binpack(
    const int* __restrict__ idx, const int* __restrict__ sgn,
    unsigned* __restrict__ reg, int* __restrict__ cnt) {
    const int w = threadIdx.x >> 6, lane = threadIdx.x & 63;
    const int dslice  = blockIdx.x >> 2;
    const int quarter = blockIdx.x & 3;
    const int sc      = quarter * 4 + w;
    const int d0      = dslice * SLICE + sc * SC_D;
    unsigned* regw = reg + ((size_t)(dslice * NSC + sc) * NBIN) * BCAP;
    const unsigned long long lmask = (1ull << lane) - 1ull;

    unsigned cb[16];
    #pragma unroll
    for (int b = 0; b < 16; ++b) cb[b] = 0;

    #pragma unroll
    for (int step = 0; step < SC_D / 64; ++step) {
        const int dli = step * 64 + lane;
        const int4 iv = reinterpret_cast<const int4*>(idx)[d0 + dli];
        const int4 sv = reinterpret_cast<const int4*>(sgn)[d0 + dli];
        const unsigned rowbyte = (unsigned)((sc * SC_D + dli) << 7);
        #pragma unroll
        for (int c = 0; c < 4; ++c) {
            const unsigned p = ((unsigned)((c==0)?iv.x:(c==1)?iv.y:(c==2)?iv.z:iv.w)) & 4095u;
            const unsigned s = ((unsigned)((c==0)?sv.x:(c==1)?sv.y:(c==2)?sv.z:sv.w)) & 1u;
            const unsigned e = rowbyte | ((p & 255u) << 19) | ((s ^ 1u) << 31);
            const unsigned bin = p >> 8;
            unsigned pos = 0;
            #pragma unroll
            for (int b = 0; b < 16; ++b) {
                const unsigned long long m = __ballot(bin == (unsigned)b);
                if (bin == (unsigned)b) pos = cb[b] + (unsigned)__popcll(m & lmask);
                cb[b] += (unsigned)__popcll(m);
            }
            if (pos < (unsigned)BCAP) regw[bin * BCAP + pos] = e;
        }
    }
    unsigned cval = 0;
    #pragma unroll
    for (int b = 0; b < 16; ++b) {
        const unsigned cc = cb[b] < (unsigned)BCAP ? cb[b] : (unsigned)BCAP;
        cval = (lane == b) ? cc : cval;
    }
    if (lane < 16) cnt[(dslice * NSC + sc) * NBIN + lane] = (int)cval;
}

// ---------------- K2: transpose x[64][D] -> xTh[D][64] (f16) ----------------
__global__ __launch_bounds__(256) void k_transpose(
    const float* __restrict__ x, unsigned short* __restrict__ xTh) {
    __shared__ float tile[64 * 65];
    const int d0 = blockIdx.x * 64;
    const int t = threadIdx.x;
    const int lane = t & 63;
    #pragma unroll
    for (int k = 0; k < 16; ++k) {
        const int b = k * 4 + (t >> 6);
        tile[lane * 65 + b] = x[(size_t)b * D_DIM + d0 + lane];
    }
    __syncthreads();
    #pragma unroll
    for (int k = 0; k < 16; ++k) {
        const int dr = k * 4 + (t >> 6);
        const __half h = __float2half_rn(tile[dr * 65 + lane]);
        xTh[(size_t)(d0 + dr) * B_DIM + lane] = __builtin_bit_cast(unsigned short, h);
    }
}

// ---------------- K3: rebin + register-accumulator process ----------------
// u16 queue entry: bits 0-7 dloc-in-sc, 8-11 po (0..15), 14 dummy, 15 negate.
__global__ __launch_bounds__(512, 8) void k_process(
    const unsigned* __restrict__ reg, const int* __restrict__ cnt,
    const unsigned short* __restrict__ xTh, __half* __restrict__ part) {
    __shared__ unsigned short q[WPB][NSC][QCAP];   // [target][sc] 7 KB
    __shared__ short qcnt[WPB][NSC];               // padded counts (x4)

    const int w = threadIdx.x >> 6, lane = threadIdx.x & 63;
    const int dg  = blockIdx.x >> 5;      // 0..31 (32 consecutive blocks share dg)
    const int hb  = blockIdx.x & 31;      // 0..31
    const int bin = hb >> 1, half = hb & 1;
    const unsigned long long lmask = (1ull << lane) - 1ull;
    const int lane2 = lane * 2;

    __half a0{}, a1{}, a2{}, a3{}, a4{}, a5{}, a6{}, a7{};
    __half a8{}, a9{}, a10{}, a11{}, a12{}, a13{}, a14{}, a15{};

    // scalar-branched accumulate (po is wave-uniform -> s_cmp/s_cbranch)
    auto ADD = [&](unsigned e, unsigned short u) {
        if (!(e & 0x4000u)) {
            const unsigned short uv = u ^ (unsigned short)(e & 0x8000u);
            const __half hv = __builtin_bit_cast(__half, uv);
            const unsigned po = (e >> 8) & 15u;
            if (po < 8u) {
                if (po < 4u) {
                    if (po < 2u) { if (po == 0u) a0 = __hadd(a0, hv); else a1 = __hadd(a1, hv); }
                    else         { if (po == 2u) a2 = __hadd(a2, hv); else a3 = __hadd(a3, hv); }
                } else {
                    if (po < 6u) { if (po == 4u) a4 = __hadd(a4, hv); else a5 = __hadd(a5, hv); }
                    else         { if (po == 6u) a6 = __hadd(a6, hv); else a7 = __hadd(a7, hv); }
                }
            } else {
                if (po < 12u) {
                    if (po < 10u) { if (po == 8u)  a8 = __hadd(a8, hv);  else a9 = __hadd(a9, hv); }
                    else          { if (po == 10u) a10 = __hadd(a10, hv); else a11 = __hadd(a11, hv); }
                } else {
                    if (po < 14u) { if (po == 12u) a12 = __hadd(a12, hv); else a13 = __hadd(a13, hv); }
                    else          { if (po == 14u) a14 = __hadd(a14, hv); else a15 = __hadd(a15, hv); }
                }
            }
        }
    };

    for (int ds_i = 0; ds_i < G_DS; ++ds_i) {
        const int dslice = dg * G_DS + ds_i;

        // --- rebin: wave w handles sc = 2w, 2w+1 ---
        #pragma unroll
        for (int sc2 = 0; sc2 < 2; ++sc2) {
            const int sc = 2 * w + sc2;
            const int n  = cnt[(dslice * NSC + sc) * NBIN + bin];
            const unsigned* list = reg + (size_t)((dslice * NSC + sc) * NBIN + bin) * BCAP;
            unsigned c0 = 0, c1 = 0, c2 = 0, c3 = 0, c4 = 0, c5 = 0, c6 = 0, c7 = 0;
            for (int base = 0; base < n; base += 64) {
                const int i = base + lane;
                const unsigned e = (i < n) ? list[i] : 0u;
                const bool valid = (i < n) && (((e >> 26) & 1u) == (unsigned)half);
                const unsigned t = valid ? ((e >> 23) & 7u) : 0xFFu;
                const unsigned long long m0 = __ballot(t == 0u);
                const unsigned long long m1 = __ballot(t == 1u);
                const unsigned long long m2 = __ballot(t == 2u);
                const unsigned long long m3 = __ballot(t == 3u);
                const unsigned long long m4 = __ballot(t == 4u);
                const unsigned long long m5 = __ballot(t == 5u);
                const unsigned long long m6 = __ballot(t == 6u);
                const unsigned long long m7 = __ballot(t == 7u);
                if (valid) {
                    const unsigned long long mt =
                        t < 4u ? (t < 2u ? (t == 0u ? m0 : m1) : (t == 2u ? m2 : m3))
                               : (t < 6u ? (t == 4u ? m4 : m5) : (t == 6u ? m6 : m7));
                    const unsigned cbase =
                        t < 4u ? (t < 2u ? (t == 0u ? c0 : c1) : (t == 2u ? c2 : c3))
                               : (t < 6u ? (t == 4u ? c4 : c5) : (t == 6u ? c6 : c7));
                    const unsigned pos = cbase + (unsigned)__popcll(mt & lmask);
                    const unsigned e16 = ((e >> 7) & 255u) | (((e >> 19) & 15u) << 8)
                                       | ((e >> 31) << 15);
                    if (pos < 24u) q[t][sc][pos] = (unsigned short)e16;
                }
                c0 += __popcll(m0); c1 += __popcll(m1);
                c2 += __popcll(m2); c3 += __popcll(m3);
                c4 += __popcll(m4); c5 += __popcll(m5);
                c6 += __popcll(m6); c7 += __popcll(m7);
            }
            c0 = c0 < 24u ? c0 : 24u;  c1 = c1 < 24u ? c1 : 24u;
            c2 = c2 < 24u ? c2 : 24u;  c3 = c3 < 24u ? c3 : 24u;
            c4 = c4 < 24u ? c4 : 24u;  c5 = c5 < 24u ? c5 : 24u;
            c6 = c6 < 24u ? c6 : 24u;  c7 = c7 < 24u ? c7 : 24u;
            // pad each queue to multiple of 4 with dummy (bit14) entries
            if (lane < 32) {
                const int tt = lane >> 2, j = lane & 3;
                const unsigned ct =
                    tt < 4 ? (tt < 2 ? (tt == 0 ? c0 : c1) : (tt == 2 ? c2 : c3))
                           : (tt < 6 ? (tt == 4 ? c4 : c5) : (tt == 6 ? c6 : c7));
                const unsigned ct4 = (ct + 3u) & ~3u;
                if (ct + (unsigned)j < ct4) q[tt][sc][ct + j] = (unsigned short)0x4000u;
                if (j == 0) qcnt[tt][sc] = (short)ct4;
            }
        }
        __syncthreads();

        // --- process: wave w = target w; acc in registers, lane = b ---
        const char* xs = reinterpret_cast<const char*>(xTh)
                       + (size_t)dslice * SLICE * 128;
        for (int sc = 0; sc < NSC; ++sc) {
            const int n = qcnt[w][sc];
            const unsigned short* qq = &q[w][sc][0];
            const char* xss = xs + (sc << 15);
            for (int i = 0; i < n; i += 4) {
                const unsigned w0 = *reinterpret_cast<const unsigned*>(qq + i);
                const unsigned w1 = *reinterpret_cast<const unsigned*>(qq + i + 2);
                const unsigned s0 = __builtin_amdgcn_readfirstlane(w0);
                const unsigned s1 = __builtin_amdgcn_readfirstlane(w1);
                const unsigned e0 = s0 & 0xFFFFu, e1 = s0 >> 16;
                const unsigned e2 = s1 & 0xFFFFu, e3 = s1 >> 16;
                // all 4 gathers issued before any (branchy) accumulate
                const unsigned short u0 = *reinterpret_cast<const unsigned short*>(
                    xss + ((e0 & 255u) << 7) + lane2);
                const unsigned short u1 = *reinterpret_cast<const unsigned short*>(
                    xss + ((e1 & 255u) << 7) + lane2);
                const unsigned short u2 = *reinterpret_cast<const unsigned short*>(
                    xss + ((e2 & 255u) << 7) + lane2);
                const unsigned short u3 = *reinterpret_cast<const unsigned short*>(
                    xss + ((e3 & 255u) << 7) + lane2);
                ADD(e0, u0); ADD(e1, u1); ADD(e2, u2); ADD(e3, u3);
            }
        }
        __syncthreads();   // q reused next ds iteration
    }

    // writeout: pr = hb*8 + w; part[pr][dg][po][b] (f16)
    __half* wp = part + ((size_t)((hb * WPB + w) * NDG + dg)) * (PR_W * B_DIM);
    wp[ 0 * 64 + lane] = a0;  wp[ 1 * 64 + lane] = a1;
    wp[ 2 * 64 + lane] = a2;  wp[ 3 * 64 + lane] = a3;
    wp[ 4 * 64 + lane] = a4;  wp[ 5 * 64 + lane] = a5;
    wp[ 6 * 64 + lane] = a6;  wp[ 7 * 64 + lane] = a7;
    wp[ 8 * 64 + lane] = a8;  wp[ 9 * 64 + lane] = a9;
    wp[10 * 64 + lane] = a10; wp[11 * 64 + lane] = a11;
    wp[12 * 64 + lane] = a12; wp[13 * 64 + lane] = a13;
    wp[14 * 64 + lane] = a14; wp[15 * 64 + lane] = a15;
}

// ---------------- K4: reduce partials -> out ----------------
__global__ __launch_bounds__(256) void k_reduce(
    const __half* __restrict__ part, float* __restrict__ out) {
    const int pr = blockIdx.x;       // p-range 0..255 (16 wide)
    const int t  = threadIdx.x;

    float4 acc = make_float4(0.f, 0.f, 0.f, 0.f);
    const size_t base = (size_t)pr * NDG * (PR_W * B_DIM);
    for (int dgi = 0; dgi < NDG; ++dgi) {
        const uint2 pv = *reinterpret_cast<const uint2*>(
            part + base + (size_t)dgi * (PR_W * B_DIM) + t * 4);
        const __half2 h0 = __builtin_bit_cast(__half2, pv.x);
        const __half2 h1 = __builtin_bit_cast(__half2, pv.y);
        acc.x += __half2float(h0.x); acc.y += __half2float(h0.y);
        acc.z += __half2float(h1.x); acc.w += __half2float(h1.y);
    }

    __shared__ float st[16][65];
    const int po = (t * 4) >> 6;          // 0..15
    const int b0 = (t * 4) & 63;
    st[po][b0]     = acc.x; st[po][b0 + 1] = acc.y;
    st[po][b0 + 2] = acc.z; st[po][b0 + 3] = acc.w;
    __syncthreads();

    #pragma unroll
    for (int k = 0; k < 4; ++k) {
        const int flat = k * 256 + t;     // b*16 + po
        const int b = flat >> 4, poo = flat & 15;
        out[(size_t)b * P_DIM + pr * PR_W + poo] = st[poo][b];
    }
}

// ---------------- fallback: LDS-atomic histogram ----------------
__device__ __forceinline__ float signed_val(float x, int s) {
    return __uint_as_float(__float_as_uint(x) ^ (((unsigned)(s ^ 1)) << 31));
}

__global__ __launch_bounds__(1024) void sjlt_hist_fb(
    const float* __restrict__ x, const int* __restrict__ idx,
    const int* __restrict__ sgn, float* __restrict__ out) {
    __shared__ float hist[2][P_DIM];
    for (int i = threadIdx.x; i < 2 * P_DIM; i += 1024) (&hist[0][0])[i] = 0.0f;
    __syncthreads();
    const int chunk = blockIdx.x, bg = blockIdx.y;
    const int d0 = chunk * (D_DIM / 16), b0 = bg * 2;
    const float* xr0 = x + (size_t)b0 * D_DIM + d0;
    const float* xr1 = xr0 + D_DIM;
    const int4* iv4 = reinterpret_cast<const int4*>(idx) + d0;
    const int4* sv4 = reinterpret_cast<const int4*>(sgn) + d0;
    for (int t = threadIdx.x; t < D_DIM / 16; t += 1024) {
        const int4 iv = iv4[t]; const int4 sv = sv4[t];
        const float x0 = xr0[t], x1 = xr1[t];
        unsafeAtomicAdd(&hist[0][iv.x], signed_val(x0, sv.x));
        unsafeAtomicAdd(&hist[0][iv.y], signed_val(x0, sv.y));
        unsafeAtomicAdd(&hist[0][iv.z], signed_val(x0, sv.z));
        unsafeAtomicAdd(&hist[0][iv.w], signed_val(x0, sv.w));
        unsafeAtomicAdd(&hist[1][iv.x], signed_val(x1, sv.x));
        unsafeAtomicAdd(&hist[1][iv.y], signed_val(x1, sv.y));
        unsafeAtomicAdd(&hist[1][iv.z], signed_val(x1, sv.z));
        unsafeAtomicAdd(&hist[1][iv.w], signed_val(x1, sv.w));
    }
    __syncthreads();
    float* o = out + (size_t)b0 * P_DIM;
    for (int p = threadIdx.x; p < P_DIM; p += 1024) {
        unsafeAtomicAdd(&o[p],         hist[0][p]);
        unsafeAtomicAdd(&o[P_DIM + p], hist[1][p]);
    }
}

extern "C" void kernel_launch(void* const* d_in, const int* in_sizes, int n_in,
                              void* d_out, int out_size, void* d_ws, size_t ws_size,
                              hipStream_t stream) {
    const float* x   = (const float*)d_in[0];
    const int*   idx = (const int*)d_in[1];
    const int*   sgn = (const int*)d_in[2];
    float* out = (float*)d_out;

    if (ws_size >= WS_NEED) {
        char* ws = (char*)d_ws;
        unsigned* reg = (unsigned*)(ws + REG_OFF);
        int* cnt      = (int*)(ws + CNT_OFF);
        unsigned short* xTh = (unsigned short*)(ws + XT_OFF);
        __half* part  = (__half*)(ws + PART_OFF);

        k_binpack<<<NDS * 4, 256, 0, stream>>>(idx, sgn, reg, cnt);
        k_transpose<<<D_DIM / 64, 256, 0, stream>>>(x, xTh);
        k_process<<<NHB * NDG, 512, 0, stream>>>(reg, cnt, xTh, part);
        k_reduce<<<NPR, 256, 0, stream>>>(part, out);
    } else {
        hipMemsetAsync(d_out, 0, (size_t)out_size * sizeof(float), stream);
        dim3 grid(16, 32);
        sjlt_hist_fb<<<grid, 1024, 0, stream>>>(x, idx, sgn, out);
    }
}

// Round 17
// 101.845 us; speedup vs baseline: 1.0430x; 1.0430x over previous
//
#include <hip/hip_runtime.h>
#include <hip/hip_bf16.h>
#include <hip/hip_fp16.h>

// SJLT projection: out[b, idx[d,c]] += x[b,d] * (2*sign[d,c]-1)
// B=64, D=262144, C=4, P=4096
//
// R17 = R16 with the XCD locality mapping FIXED (single change).
// R16 post-mortem: k_process 78us, FETCH_SIZE 19->60 MB. R16 mapped
// dg = blockIdx>>5 so the 32 blocks sharing one dslice-pair's 1MB xT
// region were CONSECUTIVE blockIdx -> round-robined across all 8 XCDs ->
// every XCD L2 re-fetched the region (L2-miss gathers ~300cy). Fix:
// dg = blockIdx&31 (same-dg peers stride 32 = 0 mod 8 -> same XCD),
// hb = blockIdx>>5. Everything else is R16 verbatim (proven correct):
//   - register accumulators (16 named __half per lane, lane = b),
//     scalar-branch-tree routing on wave-uniform po; no hist LDS,
//     no dup-merge, ~3 VALU/entry.
//   - queues padded to x4 with bit14-dummy entries; 4 gathers in flight.
//   - LDS 7.5 KB, launch_bounds(512,8).

constexpr int B_DIM = 64;
constexpr int D_DIM = 262144;
constexpr int P_DIM = 4096;

constexpr int NDS   = 64;
constexpr int SLICE = D_DIM / NDS;      // 4096
constexpr int NBIN  = 16;               // binpack bins (256-wide)
constexpr int NSC   = 16;               // scanners per dslice
constexpr int SC_D  = SLICE / NSC;      // 256
constexpr int BCAP  = 128;              // per (dslice,sc,bin): mean 64, 8 sigma
constexpr int NHB   = 32;               // half-bins (128-wide)
constexpr int G_DS  = 2;                // dslices per process block
constexpr int NDG   = NDS / G_DS;       // 32
constexpr int WPB   = 8;
constexpr int PR_W  = 16;
constexpr int NPR   = P_DIM / PR_W;     // 256
constexpr int QCAP  = 28;               // mean 4 (Poisson), clamp 24, pad to x4

// ---- ws layout ----
constexpr size_t REG_OFF   = 0;
constexpr size_t REG_BYTES = (size_t)NDS * NSC * NBIN * BCAP * 4;          // 8.4 MB
constexpr size_t CNT_OFF   = REG_OFF + REG_BYTES;
constexpr size_t CNT_BYTES = (size_t)NDS * NSC * NBIN * 4;                 // 64 KB
constexpr size_t XT_OFF    = CNT_OFF + CNT_BYTES;
constexpr size_t XT_BYTES  = (size_t)D_DIM * B_DIM * 2;                    // 33.5 MB
constexpr size_t PART_OFF  = XT_OFF + XT_BYTES;
constexpr size_t PART_BYTES = (size_t)NPR * NDG * PR_W * B_DIM * 2;        // 16.8 MB
constexpr size_t WS_NEED   = PART_OFF + PART_BYTES;                        // ~59 MB

// ---------------- K1: one-pass pack + bin (proven) ----------------
// entry u32: bits 0-18 rowbyte (dloc-in-slice*128), 19-26 p&255,
//            bit 31 = (sv^1) -> negate when set.
__global__ __launch_bounds__(256) void k_binpack(
    const int* __restrict__ idx, const int* __restrict__ sgn,
    unsigned* __restrict__ reg, int* __restrict__ cnt) {
    const int w = threadIdx.x >> 6, lane = threadIdx.x & 63;
    const int dslice  = blockIdx.x >> 2;
    const int quarter = blockIdx.x & 3;
    const int sc      = quarter * 4 + w;
    const int d0      = dslice * SLICE + sc * SC_D;
    unsigned* regw = reg + ((size_t)(dslice * NSC + sc) * NBIN) * BCAP;
    const unsigned long long lmask = (1ull << lane) - 1ull;

    unsigned cb[16];
    #pragma unroll
    for (int b = 0; b < 16; ++b) cb[b] = 0;

    #pragma unroll
    for (int step = 0; step < SC_D / 64; ++step) {
        const int dli = step * 64 + lane;
        const int4 iv = reinterpret_cast<const int4*>(idx)[d0 + dli];
        const int4 sv = reinterpret_cast<const int4*>(sgn)[d0 + dli];
        const unsigned rowbyte = (unsigned)((sc * SC_D + dli) << 7);
        #pragma unroll
        for (int c = 0; c < 4; ++c) {
            const unsigned p = ((unsigned)((c==0)?iv.x:(c==1)?iv.y:(c==2)?iv.z:iv.w)) & 4095u;
            const unsigned s = ((unsigned)((c==0)?sv.x:(c==1)?sv.y:(c==2)?sv.z:sv.w)) & 1u;
            const unsigned e = rowbyte | ((p & 255u) << 19) | ((s ^ 1u) << 31);
            const unsigned bin = p >> 8;
            unsigned pos = 0;
            #pragma unroll
            for (int b = 0; b < 16; ++b) {
                const unsigned long long m = __ballot(bin == (unsigned)b);
                if (bin == (unsigned)b) pos = cb[b] + (unsigned)__popcll(m & lmask);
                cb[b] += (unsigned)__popcll(m);
            }
            if (pos < (unsigned)BCAP) regw[bin * BCAP + pos] = e;
        }
    }
    unsigned cval = 0;
    #pragma unroll
    for (int b = 0; b < 16; ++b) {
        const unsigned cc = cb[b] < (unsigned)BCAP ? cb[b] : (unsigned)BCAP;
        cval = (lane == b) ? cc : cval;
    }
    if (lane < 16) cnt[(dslice * NSC + sc) * NBIN + lane] = (int)cval;
}

// ---------------- K2: transpose x[64][D] -> xTh[D][64] (f16) ----------------
__global__ __launch_bounds__(256) void k_transpose(
    const float* __restrict__ x, unsigned short* __restrict__ xTh) {
    __shared__ float tile[64 * 65];
    const int d0 = blockIdx.x * 64;
    const int t = threadIdx.x;
    const int lane = t & 63;
    #pragma unroll
    for (int k = 0; k < 16; ++k) {
        const int b = k * 4 + (t >> 6);
        tile[lane * 65 + b] = x[(size_t)b * D_DIM + d0 + lane];
    }
    __syncthreads();
    #pragma unroll
    for (int k = 0; k < 16; ++k) {
        const int dr = k * 4 + (t >> 6);
        const __half h = __float2half_rn(tile[dr * 65 + lane]);
        xTh[(size_t)(d0 + dr) * B_DIM + lane] = __builtin_bit_cast(unsigned short, h);
    }
}

// ---------------- K3: rebin + register-accumulator process ----------------
// u16 queue entry: bits 0-7 dloc-in-sc, 8-11 po (0..15), 14 dummy, 15 negate.
__global__ __launch_bounds__(512, 8) void k_process(
    const unsigned* __restrict__ reg, const int* __restrict__ cnt,
    const unsigned short* __restrict__ xTh, __half* __restrict__ part) {
    __shared__ unsigned short q[WPB][NSC][QCAP];   // [target][sc] 7 KB
    __shared__ short qcnt[WPB][NSC];               // padded counts (x4)

    const int w = threadIdx.x >> 6, lane = threadIdx.x & 63;
    const int dg  = blockIdx.x & 31;      // FIXED: stride-32 peers -> same XCD
    const int hb  = blockIdx.x >> 5;      // 0..31
    const int bin = hb >> 1, half = hb & 1;
    const unsigned long long lmask = (1ull << lane) - 1ull;
    const int lane2 = lane * 2;

    __half a0{}, a1{}, a2{}, a3{}, a4{}, a5{}, a6{}, a7{};
    __half a8{}, a9{}, a10{}, a11{}, a12{}, a13{}, a14{}, a15{};

    // scalar-branched accumulate (po is wave-uniform -> s_cmp/s_cbranch)
    auto ADD = [&](unsigned e, unsigned short u) {
        if (!(e & 0x4000u)) {
            const unsigned short uv = u ^ (unsigned short)(e & 0x8000u);
            const __half hv = __builtin_bit_cast(__half, uv);
            const unsigned po = (e >> 8) & 15u;
            if (po < 8u) {
                if (po < 4u) {
                    if (po < 2u) { if (po == 0u) a0 = __hadd(a0, hv); else a1 = __hadd(a1, hv); }
                    else         { if (po == 2u) a2 = __hadd(a2, hv); else a3 = __hadd(a3, hv); }
                } else {
                    if (po < 6u) { if (po == 4u) a4 = __hadd(a4, hv); else a5 = __hadd(a5, hv); }
                    else         { if (po == 6u) a6 = __hadd(a6, hv); else a7 = __hadd(a7, hv); }
                }
            } else {
                if (po < 12u) {
                    if (po < 10u) { if (po == 8u)  a8 = __hadd(a8, hv);  else a9 = __hadd(a9, hv); }
                    else          { if (po == 10u) a10 = __hadd(a10, hv); else a11 = __hadd(a11, hv); }
                } else {
                    if (po < 14u) { if (po == 12u) a12 = __hadd(a12, hv); else a13 = __hadd(a13, hv); }
                    else          { if (po == 14u) a14 = __hadd(a14, hv); else a15 = __hadd(a15, hv); }
                }
            }
        }
    };

    for (int ds_i = 0; ds_i < G_DS; ++ds_i) {
        const int dslice = dg * G_DS + ds_i;

        // --- rebin: wave w handles sc = 2w, 2w+1 ---
        #pragma unroll
        for (int sc2 = 0; sc2 < 2; ++sc2) {
            const int sc = 2 * w + sc2;
            const int n  = cnt[(dslice * NSC + sc) * NBIN + bin];
            const unsigned* list = reg + (size_t)((dslice * NSC + sc) * NBIN + bin) * BCAP;
            unsigned c0 = 0, c1 = 0, c2 = 0, c3 = 0, c4 = 0, c5 = 0, c6 = 0, c7 = 0;
            for (int base = 0; base < n; base += 64) {
                const int i = base + lane;
                const unsigned e = (i < n) ? list[i] : 0u;
                const bool valid = (i < n) && (((e >> 26) & 1u) == (unsigned)half);
                const unsigned t = valid ? ((e >> 23) & 7u) : 0xFFu;
                const unsigned long long m0 = __ballot(t == 0u);
                const unsigned long long m1 = __ballot(t == 1u);
                const unsigned long long m2 = __ballot(t == 2u);
                const unsigned long long m3 = __ballot(t == 3u);
                const unsigned long long m4 = __ballot(t == 4u);
                const unsigned long long m5 = __ballot(t == 5u);
                const unsigned long long m6 = __ballot(t == 6u);
                const unsigned long long m7 = __ballot(t == 7u);
                if (valid) {
                    const unsigned long long mt =
                        t < 4u ? (t < 2u ? (t == 0u ? m0 : m1) : (t == 2u ? m2 : m3))
                               : (t < 6u ? (t == 4u ? m4 : m5) : (t == 6u ? m6 : m7));
                    const unsigned cbase =
                        t < 4u ? (t < 2u ? (t == 0u ? c0 : c1) : (t == 2u ? c2 : c3))
                               : (t < 6u ? (t == 4u ? c4 : c5) : (t == 6u ? c6 : c7));
                    const unsigned pos = cbase + (unsigned)__popcll(mt & lmask);
                    const unsigned e16 = ((e >> 7) & 255u) | (((e >> 19) & 15u) << 8)
                                       | ((e >> 31) << 15);
                    if (pos < 24u) q[t][sc][pos] = (unsigned short)e16;
                }
                c0 += __popcll(m0); c1 += __popcll(m1);
                c2 += __popcll(m2); c3 += __popcll(m3);
                c4 += __popcll(m4); c5 += __popcll(m5);
                c6 += __popcll(m6); c7 += __popcll(m7);
            }
            c0 = c0 < 24u ? c0 : 24u;  c1 = c1 < 24u ? c1 : 24u;
            c2 = c2 < 24u ? c2 : 24u;  c3 = c3 < 24u ? c3 : 24u;
            c4 = c4 < 24u ? c4 : 24u;  c5 = c5 < 24u ? c5 : 24u;
            c6 = c6 < 24u ? c6 : 24u;  c7 = c7 < 24u ? c7 : 24u;
            // pad each queue to multiple of 4 with dummy (bit14) entries
            if (lane < 32) {
                const int tt = lane >> 2, j = lane & 3;
                const unsigned ct =
                    tt < 4 ? (tt < 2 ? (tt == 0 ? c0 : c1) : (tt == 2 ? c2 : c3))
                           : (tt < 6 ? (tt == 4 ? c4 : c5) : (tt == 6 ? c6 : c7));
                const unsigned ct4 = (ct + 3u) & ~3u;
                if (ct + (unsigned)j < ct4) q[tt][sc][ct + j] = (unsigned short)0x4000u;
                if (j == 0) qcnt[tt][sc] = (short)ct4;
            }
        }
        __syncthreads();

        // --- process: wave w = target w; acc in registers, lane = b ---
        const char* xs = reinterpret_cast<const char*>(xTh)
                       + (size_t)dslice * SLICE * 128;
        for (int sc = 0; sc < NSC; ++sc) {
            const int n = qcnt[w][sc];
            const unsigned short* qq = &q[w][sc][0];
            const char* xss = xs + (sc << 15);
            for (int i = 0; i < n; i += 4) {
                const unsigned w0 = *reinterpret_cast<const unsigned*>(qq + i);
                const unsigned w1 = *reinterpret_cast<const unsigned*>(qq + i + 2);
                const unsigned s0 = __builtin_amdgcn_readfirstlane(w0);
                const unsigned s1 = __builtin_amdgcn_readfirstlane(w1);
                const unsigned e0 = s0 & 0xFFFFu, e1 = s0 >> 16;
                const unsigned e2 = s1 & 0xFFFFu, e3 = s1 >> 16;
                // all 4 gathers issued before any (branchy) accumulate
                const unsigned short u0 = *reinterpret_cast<const unsigned short*>(
                    xss + ((e0 & 255u) << 7) + lane2);
                const unsigned short u1 = *reinterpret_cast<const unsigned short*>(
                    xss + ((e1 & 255u) << 7) + lane2);
                const unsigned short u2 = *reinterpret_cast<const unsigned short*>(
                    xss + ((e2 & 255u) << 7) + lane2);
                const unsigned short u3 = *reinterpret_cast<const unsigned short*>(
                    xss + ((e3 & 255u) << 7) + lane2);
                ADD(e0, u0); ADD(e1, u1); ADD(e2, u2); ADD(e3, u3);
            }
        }
        __syncthreads();   // q reused next ds iteration
    }

    // writeout: pr = hb*8 + w; part[pr][dg][po][b] (f16)
    __half* wp = part + ((size_t)((hb * WPB + w) * NDG + dg)) * (PR_W * B_DIM);
    wp[ 0 * 64 + lane] = a0;  wp[ 1 * 64 + lane] = a1;
    wp[ 2 * 64 + lane] = a2;  wp[ 3 * 64 + lane] = a3;
    wp[ 4 * 64 + lane] = a4;  wp[ 5 * 64 + lane] = a5;
    wp[ 6 * 64 + lane] = a6;  wp[ 7 * 64 + lane] = a7;
    wp[ 8 * 64 + lane] = a8;  wp[ 9 * 64 + lane] = a9;
    wp[10 * 64 + lane] = a10; wp[11 * 64 + lane] = a11;
    wp[12 * 64 + lane] = a12; wp[13 * 64 + lane] = a13;
    wp[14 * 64 + lane] = a14; wp[15 * 64 + lane] = a15;
}

// ---------------- K4: reduce partials -> out ----------------
__global__ __launch_bounds__(256) void k_reduce(
    const __half* __restrict__ part, float* __restrict__ out) {
    const int pr = blockIdx.x;       // p-range 0..255 (16 wide)
    const int t  = threadIdx.x;

    float4 acc = make_float4(0.f, 0.f, 0.f, 0.f);
    const size_t base = (size_t)pr * NDG * (PR_W * B_DIM);
    for (int dgi = 0; dgi < NDG; ++dgi) {
        const uint2 pv = *reinterpret_cast<const uint2*>(
            part + base + (size_t)dgi * (PR_W * B_DIM) + t * 4);
        const __half2 h0 = __builtin_bit_cast(__half2, pv.x);
        const __half2 h1 = __builtin_bit_cast(__half2, pv.y);
        acc.x += __half2float(h0.x); acc.y += __half2float(h0.y);
        acc.z += __half2float(h1.x); acc.w += __half2float(h1.y);
    }

    __shared__ float st[16][65];
    const int po = (t * 4) >> 6;          // 0..15
    const int b0 = (t * 4) & 63;
    st[po][b0]     = acc.x; st[po][b0 + 1] = acc.y;
    st[po][b0 + 2] = acc.z; st[po][b0 + 3] = acc.w;
    __syncthreads();

    #pragma unroll
    for (int k = 0; k < 4; ++k) {
        const int flat = k * 256 + t;     // b*16 + po
        const int b = flat >> 4, poo = flat & 15;
        out[(size_t)b * P_DIM + pr * PR_W + poo] = st[poo][b];
    }
}

// ---------------- fallback: LDS-atomic histogram ----------------
__device__ __forceinline__ float signed_val(float x, int s) {
    return __uint_as_float(__float_as_uint(x) ^ (((unsigned)(s ^ 1)) << 31));
}

__global__ __launch_bounds__(1024) void sjlt_hist_fb(
    const float* __restrict__ x, const int* __restrict__ idx,
    const int* __restrict__ sgn, float* __restrict__ out) {
    __shared__ float hist[2][P_DIM];
    for (int i = threadIdx.x; i < 2 * P_DIM; i += 1024) (&hist[0][0])[i] = 0.0f;
    __syncthreads();
    const int chunk = blockIdx.x, bg = blockIdx.y;
    const int d0 = chunk * (D_DIM / 16), b0 = bg * 2;
    const float* xr0 = x + (size_t)b0 * D_DIM + d0;
    const float* xr1 = xr0 + D_DIM;
    const int4* iv4 = reinterpret_cast<const int4*>(idx) + d0;
    const int4* sv4 = reinterpret_cast<const int4*>(sgn) + d0;
    for (int t = threadIdx.x; t < D_DIM / 16; t += 1024) {
        const int4 iv = iv4[t]; const int4 sv = sv4[t];
        const float x0 = xr0[t], x1 = xr1[t];
        unsafeAtomicAdd(&hist[0][iv.x], signed_val(x0, sv.x));
        unsafeAtomicAdd(&hist[0][iv.y], signed_val(x0, sv.y));
        unsafeAtomicAdd(&hist[0][iv.z], signed_val(x0, sv.z));
        unsafeAtomicAdd(&hist[0][iv.w], signed_val(x0, sv.w));
        unsafeAtomicAdd(&hist[1][iv.x], signed_val(x1, sv.x));
        unsafeAtomicAdd(&hist[1][iv.y], signed_val(x1, sv.y));
        unsafeAtomicAdd(&hist[1][iv.z], signed_val(x1, sv.z));
        unsafeAtomicAdd(&hist[1][iv.w], signed_val(x1, sv.w));
    }
    __syncthreads();
    float* o = out + (size_t)b0 * P_DIM;
    for (int p = threadIdx.x; p < P_DIM; p += 1024) {
        unsafeAtomicAdd(&o[p],         hist[0][p]);
        unsafeAtomicAdd(&o[P_DIM + p], hist[1][p]);
    }
}

extern "C" void kernel_launch(void* const* d_in, const int* in_sizes, int n_in,
                              void* d_out, int out_size, void* d_ws, size_t ws_size,
                              hipStream_t stream) {
    const float* x   = (const float*)d_in[0];
    const int*   idx = (const int*)d_in[1];
    const int*   sgn = (const int*)d_in[2];
    float* out = (float*)d_out;

    if (ws_size >= WS_NEED) {
        char* ws = (char*)d_ws;
        unsigned* reg = (unsigned*)(ws + REG_OFF);
        int* cnt      = (int*)(ws + CNT_OFF);
        unsigned short* xTh = (unsigned short*)(ws + XT_OFF);
        __half* part  = (__half*)(ws + PART_OFF);

        k_binpack<<<NDS * 4, 256, 0, stream>>>(idx, sgn, reg, cnt);
        k_transpose<<<D_DIM / 64, 256, 0, stream>>>(x, xTh);
        k_process<<<NHB * NDG, 512, 0, stream>>>(reg, cnt, xTh, part);
        k_reduce<<<NPR, 256, 0, stream>>>(part, out);
    } else {
        hipMemsetAsync(d_out, 0, (size_t)out_size * sizeof(float), stream);
        dim3 grid(16, 32);
        sjlt_hist_fb<<<grid, 1024, 0, stream>>>(x, idx, sgn, out);
    }
}

// Round 18
// 72.375 us; speedup vs baseline: 1.4676x; 1.4072x over previous
//
#include <hip/hip_runtime.h>
#include <hip/hip_bf16.h>
#include <hip/hip_fp16.h>

// SJLT projection: out[b, idx[d,c]] += x[b,d] * (2*sign[d,c]-1)
// B=64, D=262144, C=4, P=4096
//
// R18: consolidation. R14-R17 structural gambles all lost to R13's
// k_process (41us). Revert to R13's proven process + two validated deltas:
//   1. xT in f16: pair decode = dword XOR signmask (kills f32-extract +
//      cvt_pkrtz chain; f16 also more precise than bf16).
//   2. k_prep = binpack + transpose MERGED in one kernel (independent
//      workloads, shared BW window: ~22.5us serial -> ~18us).
// Everything else R13 verbatim (grid 1024 process blocks, dslice =
// blockIdx&63 XCD mapping, QCAP_E=28, f16 partials, R13 reduce).

constexpr int B_DIM = 64;
constexpr int D_DIM = 262144;
constexpr int P_DIM = 4096;

constexpr int NDS   = 64;
constexpr int SLICE = D_DIM / NDS;      // 4096 d per dslice
constexpr int NBIN  = 16;               // p-bins of 256
constexpr int NSC   = 16;               // scanners per dslice
constexpr int SC_D  = SLICE / NSC;      // 256
constexpr int BCAP  = 128;              // entries per (dslice,sc,bin): mean 64, 8 sigma
constexpr int WPB   = 8;
constexpr int PR_W  = 32;
constexpr int NPR   = P_DIM / PR_W;     // 128
constexpr int QCAP_E = 28;              // u16 entries per (target,sc): mean 8, 7.1 sigma

constexpr int TRANS_BLOCKS = D_DIM / 64;   // 4096
constexpr int BINPK_BLOCKS = NDS * 4;      // 256

// ---- ws layout ----
constexpr size_t REG_OFF   = 0;
constexpr size_t REG_BYTES = (size_t)NDS * NSC * NBIN * BCAP * 4;          // 8.4 MB
constexpr size_t CNT_OFF   = REG_OFF + REG_BYTES;
constexpr size_t CNT_BYTES = (size_t)NDS * NSC * NBIN * 4;                 // 64 KB
constexpr size_t XT_OFF    = CNT_OFF + CNT_BYTES;
constexpr size_t XT_BYTES  = (size_t)D_DIM * B_DIM * 2;                    // 33.5 MB
constexpr size_t PART_OFF  = XT_OFF + XT_BYTES;
constexpr size_t PART_BYTES = (size_t)NPR * NDS * PR_W * B_DIM * 2;        // 33.5 MB
constexpr size_t WS_NEED   = PART_OFF + PART_BYTES;                        // ~76 MB

// ---------------- K1: merged transpose (f16) + binpack ----------------
// binpack entry u32: bits 0-18 rowbyte (dloc-in-slice*128), 19-26 p&255,
//                    bit 31 = (sv^1) -> negate when set.
__global__ __launch_bounds__(256) void k_prep(
    const float* __restrict__ x,
    const int* __restrict__ idx, const int* __restrict__ sgn,
    unsigned short* __restrict__ xTh,
    unsigned* __restrict__ reg, int* __restrict__ cnt) {
    __shared__ float tile[64 * 65];
    const int t = threadIdx.x;
    const int lane = t & 63;

    if (blockIdx.x < TRANS_BLOCKS) {
        // ---- transpose x[64][D] -> xTh[D][64] (f16) ----
        const int d0 = blockIdx.x * 64;
        #pragma unroll
        for (int k = 0; k < 16; ++k) {
            const int b = k * 4 + (t >> 6);
            tile[lane * 65 + b] = x[(size_t)b * D_DIM + d0 + lane];
        }
        __syncthreads();
        #pragma unroll
        for (int k = 0; k < 16; ++k) {
            const int dr = k * 4 + (t >> 6);
            const __half h = __float2half_rn(tile[dr * 65 + lane]);
            xTh[(size_t)(d0 + dr) * B_DIM + lane] = __builtin_bit_cast(unsigned short, h);
        }
        return;
    }

    // ---- binpack: one-pass pack + ballot-bin ----
    const int bid = blockIdx.x - TRANS_BLOCKS;   // 0..255
    const int w = t >> 6;
    const int dslice  = bid >> 2;
    const int quarter = bid & 3;
    const int sc      = quarter * 4 + w;
    const int d0      = dslice * SLICE + sc * SC_D;
    unsigned* regw = reg + ((size_t)(dslice * NSC + sc) * NBIN) * BCAP;
    const unsigned long long lmask = (1ull << lane) - 1ull;

    unsigned cb[16];
    #pragma unroll
    for (int b = 0; b < 16; ++b) cb[b] = 0;

    #pragma unroll
    for (int step = 0; step < SC_D / 64; ++step) {
        const int dli = step * 64 + lane;
        const int4 iv = reinterpret_cast<const int4*>(idx)[d0 + dli];
        const int4 sv = reinterpret_cast<const int4*>(sgn)[d0 + dli];
        const unsigned rowbyte = (unsigned)((sc * SC_D + dli) << 7);
        #pragma unroll
        for (int c = 0; c < 4; ++c) {
            const unsigned p = ((unsigned)((c==0)?iv.x:(c==1)?iv.y:(c==2)?iv.z:iv.w)) & 4095u;
            const unsigned s = ((unsigned)((c==0)?sv.x:(c==1)?sv.y:(c==2)?sv.z:sv.w)) & 1u;
            const unsigned e = rowbyte | ((p & 255u) << 19) | ((s ^ 1u) << 31);
            const unsigned bin = p >> 8;
            unsigned pos = 0;
            #pragma unroll
            for (int b = 0; b < 16; ++b) {
                const unsigned long long m = __ballot(bin == (unsigned)b);
                if (bin == (unsigned)b) pos = cb[b] + (unsigned)__popcll(m & lmask);
                cb[b] += (unsigned)__popcll(m);
            }
            if (pos < (unsigned)BCAP) regw[bin * BCAP + pos] = e;
        }
    }
    unsigned cval = 0;
    #pragma unroll
    for (int b = 0; b < 16; ++b) {
        const unsigned cc = cb[b] < (unsigned)BCAP ? cb[b] : (unsigned)BCAP;
        cval = (lane == b) ? cc : cval;
    }
    if (lane < 16) cnt[(dslice * NSC + sc) * NBIN + lane] = (int)cval;
}

// ---------------- K3: re-bin + scalarized paired process (R13) ----------
// u16 queue entry: bits 0-7 dloc within scanner, 8-12 poff (0..31),
//                  bit 15 = negate.
__global__ __launch_bounds__(512, 8) void k_process(
    const unsigned* __restrict__ reg, const int* __restrict__ cnt,
    const unsigned short* __restrict__ xTh, __half* __restrict__ part) {
    __shared__ __half2 hist[WPB][PR_W * 32];              // 32 KB
    __shared__ unsigned short q[WPB][NSC][QCAP_E];        // 7 KB
    __shared__ short qcnt[WPB][NSC];

    const int w = threadIdx.x >> 6, lane = threadIdx.x & 63;
    const int dslice = blockIdx.x & 63;     // stride-64 peers share xTh slice/XCD
    const int bin    = blockIdx.x >> 6;     // 0..15

    __half2* h2 = hist[w];
    {
        unsigned* h32 = reinterpret_cast<unsigned*>(h2);
        #pragma unroll
        for (int k = 0; k < 16; ++k) h32[k * 64 + lane] = 0u;
    }

    const unsigned long long lmask = (1ull << lane) - 1ull;

    // --- re-bin: wave w handles scanners 2w, 2w+1 ---
    #pragma unroll
    for (int h = 0; h < 2; ++h) {
        const int sc = 2 * w + h;
        const int n  = cnt[(dslice * NSC + sc) * NBIN + bin];
        const unsigned* list = reg + ((size_t)((dslice * NSC + sc) * NBIN + bin)) * BCAP;
        unsigned qc[8];
        #pragma unroll
        for (int b = 0; b < 8; ++b) qc[b] = 0;
        for (int base = 0; base < n; base += 64) {
            const int i = base + lane;
            const bool valid = i < n;
            const unsigned e = valid ? list[i] : 0u;
            const unsigned t = valid ? ((e >> 24) & 7u) : 8u;
            const unsigned e16 = ((e >> 7) & 255u) | (((e >> 19) & 31u) << 8)
                               | ((e >> 31) << 15);
            unsigned pos = 0;
            #pragma unroll
            for (int b = 0; b < 8; ++b) {
                const unsigned long long m = __ballot(t == (unsigned)b);
                if (t == (unsigned)b) pos = qc[b] + (unsigned)__popcll(m & lmask);
                qc[b] += (unsigned)__popcll(m);
            }
            if (valid && pos < (unsigned)QCAP_E)
                q[t][sc][pos] = (unsigned short)e16;
        }
        unsigned cval = 0;
        #pragma unroll
        for (int b = 0; b < 8; ++b) {
            const unsigned cc = qc[b] < (unsigned)QCAP_E ? qc[b] : (unsigned)QCAP_E;
            cval = (lane == b) ? cc : cval;
        }
        if (lane < 8) qcnt[lane][sc] = (short)cval;
    }
    __syncthreads();

    // --- process: wave w owns prange = bin*8 + w ---
    const char* xs_c = reinterpret_cast<const char*>(xTh) + (size_t)dslice * SLICE * 128;
    const unsigned li4 = (unsigned)(lane & 31) * 4u;
    const bool hi = lane >= 32;

    // f16 data: value = gathered dword XOR per-side sign mask. No cvt chain.
    auto pair_rmw = [&](unsigned wrd, unsigned dv) {
        const unsigned poL = (wrd >> 8) & 31u, poH = (wrd >> 24) & 31u;
        const unsigned smL = (wrd & 0x8000u)     ? 0x80008000u : 0u;
        const unsigned smH = (wrd & 0x80000000u) ? 0x80008000u : 0u;
        const unsigned pkb = dv ^ (hi ? smH : smL);
        const unsigned a = (hi ? poH : poL) * 32u + (unsigned)(lane & 31);
        if (poL != poH) {                       // uniform (scalar) branch
            const __half2 v2 = __builtin_bit_cast(__half2, pkb);
            h2[a] = __hadd2(h2[a], v2);
        } else {
            // rare collision: combine across halves in-register; lo half RMWs.
            const unsigned other = (unsigned)__shfl((int)pkb, (lane & 31) + 32);
            if (!hi) {
                const __half2 vsum = __hadd2(__builtin_bit_cast(__half2, pkb),
                                             __builtin_bit_cast(__half2, other));
                h2[a] = __hadd2(h2[a], vsum);
            }
        }
    };

    for (int s = 0; s < NSC; ++s) {
        const int n = qcnt[w][s];
        const unsigned* qs32 = reinterpret_cast<const unsigned*>(&q[w][s][0]);
        const unsigned sb = (unsigned)s << 15;   // s * 256 rows * 128 B
        int i = 0;
        for (; i + 4 <= n; i += 4) {             // 2 pair-ops, 2 gathers in flight
            const unsigned wa = __builtin_amdgcn_readfirstlane(qs32[i >> 1]);
            const unsigned wb = __builtin_amdgcn_readfirstlane(qs32[(i >> 1) + 1]);
            const unsigned vaA = sb + ((hi ? (wa >> 16) : wa) & 255u) * 128u + li4;
            const unsigned vaB = sb + ((hi ? (wb >> 16) : wb) & 255u) * 128u + li4;
            const unsigned dA = *reinterpret_cast<const unsigned*>(xs_c + vaA);
            const unsigned dB = *reinterpret_cast<const unsigned*>(xs_c + vaB);
            pair_rmw(wa, dA);
            pair_rmw(wb, dB);
        }
        for (; i + 2 <= n; i += 2) {
            const unsigned wa = __builtin_amdgcn_readfirstlane(qs32[i >> 1]);
            const unsigned va = sb + ((hi ? (wa >> 16) : wa) & 255u) * 128u + li4;
            pair_rmw(wa, *reinterpret_cast<const unsigned*>(xs_c + va));
        }
        if (i < n) {                             // odd tail: half-wave op
            const unsigned e0 = __builtin_amdgcn_readfirstlane((unsigned)q[w][s][i]);
            if (!hi) {
                const unsigned va = sb + (e0 & 255u) * 128u + li4;
                const unsigned dv = *reinterpret_cast<const unsigned*>(xs_c + va);
                const unsigned pkb = dv ^ ((e0 & 0x8000u) ? 0x80008000u : 0u);
                const __half2 v2 = __builtin_bit_cast(__half2, pkb);
                const unsigned a = ((e0 >> 8) & 31u) * 32u + (unsigned)(lane & 31);
                h2[a] = __hadd2(h2[a], v2);
            }
        }
    }

    // partials (f16, layout poff*64 + b, 1024 dwords/wave)
    unsigned* wp32 = reinterpret_cast<unsigned*>(
        part + ((size_t)((bin * WPB + w) * NDS + dslice)) * (PR_W * B_DIM));
    const unsigned* h32 = reinterpret_cast<const unsigned*>(h2);
    #pragma unroll
    for (int k = 0; k < 16; ++k)
        wp32[k * 64 + lane] = h32[k * 64 + lane];
}

// ---------------- K4: reduce partials -> out (R13) ----------------
__global__ __launch_bounds__(256) void k_reduce(
    const __half* __restrict__ part, float* __restrict__ out) {
    const int pr = blockIdx.x;       // p-range 0..127
    const int pq = blockIdx.y;       // poff half 0..1
    const int t  = threadIdx.x;

    float4 acc = make_float4(0.f, 0.f, 0.f, 0.f);
    const size_t base = (size_t)pr * NDS * (PR_W * B_DIM) + (size_t)pq * 1024;
    for (int ds = 0; ds < NDS; ++ds) {
        const uint2 pv = *reinterpret_cast<const uint2*>(
            part + base + (size_t)ds * (PR_W * B_DIM) + t * 4);
        const __half2 h0 = __builtin_bit_cast(__half2, pv.x);
        const __half2 h1 = __builtin_bit_cast(__half2, pv.y);
        acc.x += __half2float(h0.x); acc.y += __half2float(h0.y);
        acc.z += __half2float(h1.x); acc.w += __half2float(h1.y);
    }

    __shared__ float st[16][65];
    const int po = (t * 4) >> 6;
    const int b0 = (t * 4) & 63;
    st[po][b0]     = acc.x; st[po][b0 + 1] = acc.y;
    st[po][b0 + 2] = acc.z; st[po][b0 + 3] = acc.w;
    __syncthreads();

    #pragma unroll
    for (int k = 0; k < 4; ++k) {
        const int flat = k * 256 + t;     // b*16 + po
        const int b = flat >> 4, poo = flat & 15;
        out[(size_t)b * P_DIM + pr * PR_W + pq * 16 + poo] = st[poo][b];
    }
}

// ---------------- fallback: LDS-atomic histogram ----------------
__device__ __forceinline__ float signed_val(float x, int s) {
    return __uint_as_float(__float_as_uint(x) ^ (((unsigned)(s ^ 1)) << 31));
}

__global__ __launch_bounds__(1024) void sjlt_hist_fb(
    const float* __restrict__ x, const int* __restrict__ idx,
    const int* __restrict__ sgn, float* __restrict__ out) {
    __shared__ float hist[2][P_DIM];
    for (int i = threadIdx.x; i < 2 * P_DIM; i += 1024) (&hist[0][0])[i] = 0.0f;
    __syncthreads();
    const int chunk = blockIdx.x, bg = blockIdx.y;
    const int d0 = chunk * (D_DIM / 16), b0 = bg * 2;
    const float* xr0 = x + (size_t)b0 * D_DIM + d0;
    const float* xr1 = xr0 + D_DIM;
    const int4* iv4 = reinterpret_cast<const int4*>(idx) + d0;
    const int4* sv4 = reinterpret_cast<const int4*>(sgn) + d0;
    for (int t = threadIdx.x; t < D_DIM / 16; t += 1024) {
        const int4 iv = iv4[t]; const int4 sv = sv4[t];
        const float x0 = xr0[t], x1 = xr1[t];
        unsafeAtomicAdd(&hist[0][iv.x], signed_val(x0, sv.x));
        unsafeAtomicAdd(&hist[0][iv.y], signed_val(x0, sv.y));
        unsafeAtomicAdd(&hist[0][iv.z], signed_val(x0, sv.z));
        unsafeAtomicAdd(&hist[0][iv.w], signed_val(x0, sv.w));
        unsafeAtomicAdd(&hist[1][iv.x], signed_val(x1, sv.x));
        unsafeAtomicAdd(&hist[1][iv.y], signed_val(x1, sv.y));
        unsafeAtomicAdd(&hist[1][iv.z], signed_val(x1, sv.z));
        unsafeAtomicAdd(&hist[1][iv.w], signed_val(x1, sv.w));
    }
    __syncthreads();
    float* o = out + (size_t)b0 * P_DIM;
    for (int p = threadIdx.x; p < P_DIM; p += 1024) {
        unsafeAtomicAdd(&o[p],         hist[0][p]);
        unsafeAtomicAdd(&o[P_DIM + p], hist[1][p]);
    }
}

extern "C" void kernel_launch(void* const* d_in, const int* in_sizes, int n_in,
                              void* d_out, int out_size, void* d_ws, size_t ws_size,
                              hipStream_t stream) {
    const float* x   = (const float*)d_in[0];
    const int*   idx = (const int*)d_in[1];
    const int*   sgn = (const int*)d_in[2];
    float* out = (float*)d_out;

    if (ws_size >= WS_NEED) {
        char* ws = (char*)d_ws;
        unsigned* reg = (unsigned*)(ws + REG_OFF);
        int* cnt      = (int*)(ws + CNT_OFF);
        unsigned short* xTh = (unsigned short*)(ws + XT_OFF);
        __half* part  = (__half*)(ws + PART_OFF);

        k_prep<<<TRANS_BLOCKS + BINPK_BLOCKS, 256, 0, stream>>>(x, idx, sgn, xTh, reg, cnt);
        k_process<<<NBIN * NDS, 512, 0, stream>>>(reg, cnt, xTh, part);
        k_reduce<<<dim3(NPR, 2), 256, 0, stream>>>(part, out);
    } else {
        hipMemsetAsync(d_out, 0, (size_t)out_size * sizeof(float), stream);
        dim3 grid(16, 32);
        sjlt_hist_fb<<<grid, 1024, 0, stream>>>(x, idx, sgn, out);
    }
}